// Round 8
// baseline (208.037 us; speedup 1.0000x reference)
//
#include <hip/hip_runtime.h>
#include <hip/hip_bf16.h>
#include <math.h>

typedef __bf16 bf16_t;
typedef __attribute__((ext_vector_type(8))) __bf16 bf16x8;
typedef __attribute__((ext_vector_type(4))) __bf16 bf16x4;
typedef __attribute__((ext_vector_type(4))) float floatx4;

// B=8, N=4096, D=CV=128. fp32 in/out; bf16 MFMA compute, fp32 accumulate.
static constexpr int NSEQ = 4096;
static constexpr int DIM  = 128;
static constexpr int BATCH = 8;
static constexpr size_t NELEM = (size_t)BATCH * NSEQ * DIM;          // 4 Mi
static constexpr size_t KV_BYTES = 2 * NELEM * sizeof(bf16_t);       // 16 MiB
// FULL split: 144 parts/batch (ceil((t+1)/4) per 128q-tile t).
// Partials: bf16, C-flat layout [part][w][h][c][lane][r] = 16384 elems;
// Lpart fp32 [part][128].
static constexpr size_t FULL_PARTS = (size_t)BATCH * 144;
static constexpr size_t WS_FULL =
    KV_BYTES + FULL_PARTS * (16384 * sizeof(bf16_t) + 128 * sizeof(float));
// 1/sqrt(128)*log2(e), folded into Q so the inner loop is bare exp2
static constexpr float SCALE_LOG2E = 0.08838834764831845f * 1.4426950408889634f;

__device__ __forceinline__ bf16x8 ld8_f32s(const float* p, float s) {
  float4 a = *(const float4*)p;
  float4 b = *(const float4*)(p + 4);
  bf16x8 r = {(__bf16)(a.x * s), (__bf16)(a.y * s), (__bf16)(a.z * s), (__bf16)(a.w * s),
              (__bf16)(b.x * s), (__bf16)(b.y * s), (__bf16)(b.z * s), (__bf16)(b.w * s)};
  return r;
}

// ---------------- prep: fragment-major bf16 K/V tiles (32-key tiles) ----------------
// Kf[tile][f=c2*4+d][lane][8]: K[key=c2*16+l16][dim=d*32+quad*8+j]
// Vf[tile][f=c   ][lane][8]: V[key=quad*8+j ][cv =c*16+l16]
__global__ __launch_bounds__(256)
void prep_kernel(const float* __restrict__ K, const float* __restrict__ V,
                 bf16_t* __restrict__ Kf, bf16_t* __restrict__ Vf) {
  __shared__ bf16_t lds[32][136];
  const int id   = blockIdx.x;                  // 2048 blocks
  const bool isV = id >= 1024;
  const int tile = isV ? id - 1024 : id;        // b*128 + kt
  const float* src = (isV ? V : K) + (size_t)tile * 32 * DIM;
  const int t = (int)threadIdx.x;
  #pragma unroll
  for (int i = 0; i < 4; ++i) {
    int f4 = t + i * 256;
    int row = f4 >> 5, c4 = f4 & 31;
    float4 v = ((const float4*)src)[f4];
    lds[row][c4 * 4 + 0] = (__bf16)v.x;
    lds[row][c4 * 4 + 1] = (__bf16)v.y;
    lds[row][c4 * 4 + 2] = (__bf16)v.z;
    lds[row][c4 * 4 + 3] = (__bf16)v.w;
  }
  __syncthreads();
  const int lane = t & 63, w = t >> 6, l16 = lane & 15, quad = lane >> 4;
  bf16_t* dst = (isV ? Vf : Kf) + (size_t)tile * 4096;
  #pragma unroll
  for (int i = 0; i < 2; ++i) {
    const int f = w + i * 4;
    bf16x8 val;
    if (!isV) {
      const int c2 = f >> 2, d = f & 3;
      val = *(const bf16x8*)&lds[c2 * 16 + l16][d * 32 + quad * 8];
    } else {
      #pragma unroll
      for (int j = 0; j < 8; ++j) val[j] = lds[quad * 8 + j][f * 16 + l16];
    }
    *(bf16x8*)(dst + f * 512 + lane * 8) = val;
  }
}

// ---------------- attention: barrier-free, global fragment streaming ----------------
// mode 2: FULL split, 1152 blocks; mode 0: direct, 256 blocks.
// No __syncthreads in the K-loop: fragments stream global(L1/L2)->VGPR; only the
// per-wave P C->A transpose uses LDS (wave-private, lgkmcnt-guarded).

__global__ __launch_bounds__(256)
void attn_kernel(const float* __restrict__ Qf, const bf16_t* __restrict__ Kf,
                 const bf16_t* __restrict__ Vf, float* __restrict__ Out,
                 bf16_t* __restrict__ Opart, float* __restrict__ Lpart, int mode) {
  __shared__ __align__(16) bf16_t Pb[4][32 * 40]; // per-wave P, 80 B rows (10 KB)

  int b, t, kt0, kt1; bool direct;
  size_t pidx = 0;
  const int id = blockIdx.x;
  if (mode == 2) {
    b = id & 7; const int e = id >> 3;            // e in [0,144)
    // group g: tiles 4g..4g+3 have g+1 parts; group base S(g)=2g(g+1)
    int g = (int)((sqrtf(2.0f * (float)e + 1.0f) - 1.0f) * 0.5f);
    while (2 * (g + 1) * (g + 2) <= e) ++g;
    while (g > 0 && 2 * g * (g + 1) > e) --g;
    const int m = g + 1, rem = e - 2 * g * (g + 1);
    const int q = rem / m;                        // tile within group
    const int part = rem - q * m;
    t = 4 * g + q;
    const int n = 4 * t + 4;                      // total 32-key tiles for t
    kt0 = (n * part) / m; kt1 = (n * (part + 1)) / m;
    direct = (m == 1);
    pidx = (size_t)b * 144 + e;
  } else {
    b = id & 7; t = id >> 3; kt0 = 0; kt1 = 4 * t + 4; direct = true;
  }

  const int tid = (int)threadIdx.x, w = tid >> 6, lane = tid & 63;
  const int l16 = lane & 15, quad = lane >> 4;
  const int q0 = t * 128 + 32 * w;                // wave's first query

  const bf16_t* Kt = Kf + (size_t)b * NSEQ * DIM + lane * 8;
  const bf16_t* Vt = Vf + (size_t)b * NSEQ * DIM + lane * 8;

  // Q A-frags: qf[h][d] = Q[q0+16h+l16][d*32+quad*8+j], scale folded
  bf16x8 qf[2][4];
  #pragma unroll
  for (int h = 0; h < 2; ++h) {
    const float* qrow = Qf + ((size_t)b * NSEQ + q0 + 16 * h + l16) * DIM + quad * 8;
    #pragma unroll
    for (int d = 0; d < 4; ++d) qf[h][d] = ld8_f32s(qrow + 32 * d, SCALE_LOG2E);
  }

  floatx4 acc[2][8];
  #pragma unroll
  for (int h = 0; h < 2; ++h)
    #pragma unroll
    for (int c = 0; c < 8; ++c) acc[h][c] = (floatx4){0.f, 0.f, 0.f, 0.f};
  float lsum[2][4] = {{0.f, 0.f, 0.f, 0.f}, {0.f, 0.f, 0.f, 0.f}};
  bf16_t* pl = Pb[w];

  for (int kt = kt0; kt < kt1; ++kt) {
    const int kb = kt * 32;
    if (kb > q0) break;               // later tiles fully masked (monotone)
    const bool diag = (kb == q0);
    const bf16_t* kbase = Kt + (size_t)kt * 4096;
    const bf16_t* vbase = Vt + (size_t)kt * 4096;

    // ---- fragment loads: 16 coalesced 1KB b128 loads, straight from L1/L2 ----
    bf16x8 kfr[8], vfr[8];
    #pragma unroll
    for (int f = 0; f < 8; ++f) kfr[f] = *(const bf16x8*)(kbase + f * 512);
    #pragma unroll
    for (int c = 0; c < 8; ++c) vfr[c] = *(const bf16x8*)(vbase + c * 512);

    // ---- S = Q K^T (32q x 32k) ----
    floatx4 s[2][2];
    #pragma unroll
    for (int h = 0; h < 2; ++h)
      #pragma unroll
      for (int c2 = 0; c2 < 2; ++c2) s[h][c2] = (floatx4){0.f, 0.f, 0.f, 0.f};
    #pragma unroll
    for (int c2 = 0; c2 < 2; ++c2)
      #pragma unroll
      for (int d = 0; d < 4; ++d) {
        const bf16x8 kf = kfr[c2 * 4 + d];
        s[0][c2] = __builtin_amdgcn_mfma_f32_16x16x32_bf16(qf[0][d], kf, s[0][c2], 0, 0, 0);
        s[1][c2] = __builtin_amdgcn_mfma_f32_16x16x32_bf16(qf[1][d], kf, s[1][c2], 0, 0, 0);
      }

    // ---- p = exp2(s); stage P for C->A transpose (wave-private LDS) ----
    #pragma unroll
    for (int h = 0; h < 2; ++h)
      #pragma unroll
      for (int c2 = 0; c2 < 2; ++c2)
        #pragma unroll
        for (int r = 0; r < 4; ++r) {
          float v = s[h][c2][r];
          if (diag)
            v = (c2 * 16 + l16 <= 16 * h + quad * 4 + r) ? v : -3.0e38f;
          float p = __builtin_amdgcn_exp2f(v);
          lsum[h][r] += p;
          pl[(h * 16 + quad * 4 + r) * 40 + c2 * 16 + l16] = (__bf16)p;
        }
    asm volatile("s_waitcnt lgkmcnt(0)" ::: "memory");
    bf16x8 pf0 = *(const bf16x8*)(pl + (l16)      * 40 + quad * 8);
    bf16x8 pf1 = *(const bf16x8*)(pl + (16 + l16) * 40 + quad * 8);

    // ---- O += P(32x32) * V(32x128) ----
    #pragma unroll
    for (int c = 0; c < 8; ++c) {
      acc[0][c] = __builtin_amdgcn_mfma_f32_16x16x32_bf16(pf0, vfr[c], acc[0][c], 0, 0, 0);
      acc[1][c] = __builtin_amdgcn_mfma_f32_16x16x32_bf16(pf1, vfr[c], acc[1][c], 0, 0, 0);
    }
  }

  // ---- epilogue ----
  if (direct) {
    float inv_l[2][4];
    #pragma unroll
    for (int h = 0; h < 2; ++h)
      #pragma unroll
      for (int r = 0; r < 4; ++r) {
        float s = lsum[h][r];
        #pragma unroll
        for (int off = 1; off < 16; off <<= 1) s += __shfl_xor(s, off, 64);
        inv_l[h][r] = 1.0f / s;
      }
    #pragma unroll
    for (int h = 0; h < 2; ++h) {
      float* orow = Out + ((size_t)b * NSEQ + q0 + 16 * h + quad * 4) * DIM + l16;
      #pragma unroll
      for (int c = 0; c < 8; ++c)
        #pragma unroll
        for (int r = 0; r < 4; ++r)
          orow[(size_t)r * DIM + c * 16] = acc[h][c][r] * inv_l[h][r];
    }
  } else {
    // bf16 partials, C-flat layout: [w][h][c][lane][r], bf16x4 stores (8 B/lane)
    bf16_t* ob = Opart + pidx * 16384;
    #pragma unroll
    for (int h = 0; h < 2; ++h) {
      #pragma unroll
      for (int c = 0; c < 8; ++c) {
        bf16x4 v = {(__bf16)acc[h][c][0], (__bf16)acc[h][c][1],
                    (__bf16)acc[h][c][2], (__bf16)acc[h][c][3]};
        *(bf16x4*)(ob + ((((size_t)w * 2 + h) * 8 + c) * 64 + lane) * 4) = v;
      }
      float* lb = Lpart + pidx * 128;
      #pragma unroll
      for (int r = 0; r < 4; ++r) {
        float s = lsum[h][r];
        #pragma unroll
        for (int off = 1; off < 16; off <<= 1) s += __shfl_xor(s, off, 64);
        if (l16 == 0) lb[32 * w + 16 * h + quad * 4 + r] = s;
      }
    }
  }
}

// ---------------- combine: sum m parts of bf16 C-flat partials ----------------
__global__ __launch_bounds__(256)
void reduce_full(const bf16_t* __restrict__ Opart, const float* __restrict__ Lpart,
                 float* __restrict__ Out) {
  __shared__ float invL[128];
  const int rb = blockIdx.x;                 // 224: b*28 + (t-4)
  const int b = rb / 28, t = 4 + rb % 28;
  const int g = t >> 2, m = g + 1;
  const size_t base = (size_t)b * 144 + 2 * g * (g + 1) + (size_t)(t - 4 * g) * m;
  const bf16_t* P = Opart + base * 16384;
  const float* L = Lpart + base * 128;
  for (int i = (int)threadIdx.x; i < 128; i += 256) {
    float l = 0.f;
    for (int p = 0; p < m; ++p) l += L[(size_t)p * 128 + i];
    invL[i] = 1.0f / l;
  }
  __syncthreads();
  float* Ob = Out + ((size_t)b * NSEQ + (size_t)t * 128) * DIM;
  for (int gi = (int)threadIdx.x; gi < 4096; gi += 256) {
    const int lane = gi & 63, c = (gi >> 6) & 7, h = (gi >> 9) & 1, w = gi >> 10;
    const int row0 = 32 * w + 16 * h + (lane >> 4) * 4;
    const int col  = c * 16 + (lane & 15);
    float4 s = {0.f, 0.f, 0.f, 0.f};
    for (int p = 0; p < m; ++p) {
      bf16x4 a = *(const bf16x4*)(P + (size_t)p * 16384 + (size_t)gi * 4);
      s.x += (float)a[0]; s.y += (float)a[1]; s.z += (float)a[2]; s.w += (float)a[3];
    }
    Ob[(size_t)(row0 + 0) * DIM + col] = s.x * invL[row0 + 0];
    Ob[(size_t)(row0 + 1) * DIM + col] = s.y * invL[row0 + 1];
    Ob[(size_t)(row0 + 2) * DIM + col] = s.z * invL[row0 + 2];
    Ob[(size_t)(row0 + 3) * DIM + col] = s.w * invL[row0 + 3];
  }
}

// ---------------- fallback (no workspace): fp32 direct ----------------
__global__ __launch_bounds__(256)
void causal_attn_fb(const float* __restrict__ Qf, const float* __restrict__ Kf,
                    const float* __restrict__ Vf, float* __restrict__ Out) {
  __shared__ bf16_t p_lds[4][16 * 72];
  const int bid = blockIdx.x, t = bid >> 3, b = bid & 7;
  const int tid = (int)threadIdx.x, wave = tid >> 6, lane = tid & 63;
  const int l16 = lane & 15, quad = lane >> 4;
  const int qtile = (wave < 2) ? t : (127 - t);
  const int q_base = qtile * 32 + (wave & 1) * 16;

  bf16x8 qf[4];
  const float* qrow = Qf + ((size_t)b * NSEQ + q_base + l16) * DIM + quad * 8;
  #pragma unroll
  for (int d = 0; d < 4; ++d) qf[d] = ld8_f32s(qrow + 32 * d, SCALE_LOG2E);

  floatx4 acc[8];
  #pragma unroll
  for (int c = 0; c < 8; ++c) acc[c] = (floatx4){0.f, 0.f, 0.f, 0.f};
  float lsum[4] = {0.f, 0.f, 0.f, 0.f};
  bf16_t* pl = p_lds[wave];
  const int ntiles = (q_base + 16 + 63) >> 6;

  for (int kt = 0; kt < ntiles; ++kt) {
    const int kb = kt * 64;
    floatx4 s[4];
    #pragma unroll
    for (int c4 = 0; c4 < 4; ++c4) s[c4] = (floatx4){0.f, 0.f, 0.f, 0.f};
    const float* kbase = Kf + ((size_t)b * NSEQ + kb + l16) * DIM + quad * 8;
    #pragma unroll
    for (int c4 = 0; c4 < 4; ++c4)
      #pragma unroll
      for (int d = 0; d < 4; ++d) {
        bf16x8 kf = ld8_f32s(kbase + (size_t)c4 * 16 * DIM + 32 * d, 1.0f);
        s[c4] = __builtin_amdgcn_mfma_f32_16x16x32_bf16(qf[d], kf, s[c4], 0, 0, 0);
      }
    #pragma unroll
    for (int c4 = 0; c4 < 4; ++c4)
      #pragma unroll
      for (int r = 0; r < 4; ++r) {
        float v = s[c4][r];
        const int qi = q_base + quad * 4 + r;
        v = (kb + c4 * 16 + l16 <= qi) ? v : -3.0e38f;
        float p = __builtin_amdgcn_exp2f(v);
        lsum[r] += p;
        pl[(quad * 4 + r) * 72 + c4 * 16 + l16] = (__bf16)p;
      }
    asm volatile("s_waitcnt lgkmcnt(0)" ::: "memory");
    bf16x8 pfA = *(const bf16x8*)(pl + l16 * 72 + quad * 8);
    bf16x8 pfB = *(const bf16x8*)(pl + l16 * 72 + 32 + quad * 8);
    const float* vb = Vf + ((size_t)b * NSEQ + kb) * DIM;
    #pragma unroll
    for (int c = 0; c < 8; ++c) {
      bf16x8 vfA, vfB;
      #pragma unroll
      for (int j = 0; j < 8; ++j) {
        vfA[j] = (__bf16)vb[(size_t)(quad * 8 + j) * DIM + c * 16 + l16];
        vfB[j] = (__bf16)vb[(size_t)(32 + quad * 8 + j) * DIM + c * 16 + l16];
      }
      acc[c] = __builtin_amdgcn_mfma_f32_16x16x32_bf16(pfA, vfA, acc[c], 0, 0, 0);
      acc[c] = __builtin_amdgcn_mfma_f32_16x16x32_bf16(pfB, vfB, acc[c], 0, 0, 0);
    }
  }
  float inv_l[4];
  #pragma unroll
  for (int r = 0; r < 4; ++r) {
    float s = lsum[r];
    #pragma unroll
    for (int off = 1; off < 16; off <<= 1) s += __shfl_xor(s, off, 64);
    inv_l[r] = 1.0f / s;
  }
  float* orow = Out + ((size_t)b * NSEQ + q_base + quad * 4) * DIM + l16;
  #pragma unroll
  for (int c = 0; c < 8; ++c)
    #pragma unroll
    for (int r = 0; r < 4; ++r)
      orow[(size_t)r * DIM + c * 16] = acc[c][r] * inv_l[r];
}

extern "C" void kernel_launch(void* const* d_in, const int* in_sizes, int n_in,
                              void* d_out, int out_size, void* d_ws, size_t ws_size,
                              hipStream_t stream) {
  const float* Q = (const float*)d_in[0];
  const float* K = (const float*)d_in[1];
  const float* V = (const float*)d_in[2];
  float* Out = (float*)d_out;
  (void)in_sizes; (void)n_in; (void)out_size;

  if (ws_size >= KV_BYTES) {
    bf16_t* Kf = (bf16_t*)d_ws;
    bf16_t* Vf = Kf + NELEM;
    prep_kernel<<<dim3(2048), dim3(256), 0, stream>>>(K, V, Kf, Vf);
    if (ws_size >= WS_FULL) {
      bf16_t* Opart = (bf16_t*)((char*)d_ws + KV_BYTES);
      float* Lpart = (float*)(Opart + FULL_PARTS * 16384);
      attn_kernel<<<dim3(1152), dim3(256), 0, stream>>>(Q, Kf, Vf, Out, Opart, Lpart, 2);
      reduce_full<<<dim3(224), dim3(256), 0, stream>>>(Opart, Lpart, Out);
    } else {
      attn_kernel<<<dim3(256), dim3(256), 0, stream>>>(Q, Kf, Vf, Out, nullptr, nullptr, 0);
    }
  } else {
    causal_attn_fb<<<dim3(512), dim3(256), 0, stream>>>(Q, K, V, Out);
  }
}

// Round 9
// 198.258 us; speedup vs baseline: 1.0493x; 1.0493x over previous
//
#include <hip/hip_runtime.h>
#include <hip/hip_bf16.h>
#include <math.h>

typedef __bf16 bf16_t;
typedef __attribute__((ext_vector_type(8))) __bf16 bf16x8;
typedef __attribute__((ext_vector_type(4))) __bf16 bf16x4;
typedef __attribute__((ext_vector_type(4))) float floatx4;

// B=8, N=4096, D=CV=128. fp32 in/out; bf16 MFMA compute, fp32 accumulate.
static constexpr int NSEQ = 4096;
static constexpr int DIM  = 128;
static constexpr int BATCH = 8;
static constexpr size_t NELEM = (size_t)BATCH * NSEQ * DIM;          // 4 Mi
static constexpr size_t KV_BYTES = 2 * NELEM * sizeof(bf16_t);       // 16 MiB
// FULL split: 144 parts/batch. Partials: bf16 row-major [part][q128][cv128];
// Lpart fp32 [part][128].
static constexpr size_t FULL_PARTS = (size_t)BATCH * 144;
static constexpr size_t WS_FULL =
    KV_BYTES + FULL_PARTS * (16384 * sizeof(bf16_t) + 128 * sizeof(float));
// 1/sqrt(128)*log2(e), folded into Q so the inner loop is bare exp2
static constexpr float SCALE_LOG2E = 0.08838834764831845f * 1.4426950408889634f;

__device__ __forceinline__ bf16x8 ld8_f32s(const float* p, float s) {
  float4 a = *(const float4*)p;
  float4 b = *(const float4*)(p + 4);
  bf16x8 r = {(__bf16)(a.x * s), (__bf16)(a.y * s), (__bf16)(a.z * s), (__bf16)(a.w * s),
              (__bf16)(b.x * s), (__bf16)(b.y * s), (__bf16)(b.z * s), (__bf16)(b.w * s)};
  return r;
}

// ---------------- prep: fragment-major bf16 K/V tiles (32-key tiles) ----------------
// Kf[tile][f=c2*4+d][lane][8]: K[key=c2*16+l16][dim=d*32+quad*8+j]
// Vf[tile][f=c   ][lane][8]: V[key=quad*8+j ][cv =c*16+l16]
__global__ __launch_bounds__(256)
void prep_kernel(const float* __restrict__ K, const float* __restrict__ V,
                 bf16_t* __restrict__ Kf, bf16_t* __restrict__ Vf) {
  __shared__ bf16_t lds[32][136];
  const int id   = blockIdx.x;                  // 2048 blocks
  const bool isV = id >= 1024;
  const int tile = isV ? id - 1024 : id;        // b*128 + kt
  const float* src = (isV ? V : K) + (size_t)tile * 32 * DIM;
  const int t = (int)threadIdx.x;
  #pragma unroll
  for (int i = 0; i < 4; ++i) {
    int f4 = t + i * 256;
    int row = f4 >> 5, c4 = f4 & 31;
    float4 v = ((const float4*)src)[f4];
    lds[row][c4 * 4 + 0] = (__bf16)v.x;
    lds[row][c4 * 4 + 1] = (__bf16)v.y;
    lds[row][c4 * 4 + 2] = (__bf16)v.z;
    lds[row][c4 * 4 + 3] = (__bf16)v.w;
  }
  __syncthreads();
  const int lane = t & 63, w = t >> 6, l16 = lane & 15, quad = lane >> 4;
  bf16_t* dst = (isV ? Vf : Kf) + (size_t)tile * 4096;
  #pragma unroll
  for (int i = 0; i < 2; ++i) {
    const int f = w + i * 4;
    bf16x8 val;
    if (!isV) {
      const int c2 = f >> 2, d = f & 3;
      val = *(const bf16x8*)&lds[c2 * 16 + l16][d * 32 + quad * 8];
    } else {
      #pragma unroll
      for (int j = 0; j < 8; ++j) val[j] = lds[quad * 8 + j][f * 16 + l16];
    }
    *(bf16x8*)(dst + f * 512 + lane * 8) = val;
  }
}

// ---------------- attention: transposed-form, barrier-free, K prefetch ----------------
// S^T = mfma(A=K, B=Q)  -> P^T[key=c2*16+quad*4+r][q=16h+l16]
// O^T = mfma(A=V, B=P^T): P^T re-layout via 4 ds_write_b64 + 2 ds_read_b128.
// acc[h][c][r] = O[q=16h+l16][cv=c*16+quad*4+r]  -> contiguous float4 epilogue.

__global__ __launch_bounds__(256)
void attn_kernel(const float* __restrict__ Qf, const bf16_t* __restrict__ Kf,
                 const bf16_t* __restrict__ Vf, float* __restrict__ Out,
                 bf16_t* __restrict__ Opart, float* __restrict__ Lpart, int mode) {
  __shared__ __align__(16) bf16_t Pb[4][32 * 40]; // per-wave P^T, 80 B rows (10 KB)

  int b, t, kt0, kt1; bool direct;
  size_t pidx = 0;
  const int id = blockIdx.x;
  if (mode == 2) {
    b = id & 7; const int e = id >> 3;            // e in [0,144)
    // group g: tiles 4g..4g+3 have g+1 parts; group base S(g)=2g(g+1)
    int g = (int)((sqrtf(2.0f * (float)e + 1.0f) - 1.0f) * 0.5f);
    while (2 * (g + 1) * (g + 2) <= e) ++g;
    while (g > 0 && 2 * g * (g + 1) > e) --g;
    const int m = g + 1, rem = e - 2 * g * (g + 1);
    const int q = rem / m;                        // tile within group
    const int part = rem - q * m;
    t = 4 * g + q;
    const int n = 4 * t + 4;                      // total 32-key tiles for t
    kt0 = (n * part) / m; kt1 = (n * (part + 1)) / m;
    direct = (m == 1);
    pidx = (size_t)b * 144 + e;
  } else {
    b = id & 7; t = id >> 3; kt0 = 0; kt1 = 4 * t + 4; direct = true;
  }

  const int tid = (int)threadIdx.x, w = tid >> 6, lane = tid & 63;
  const int l16 = lane & 15, quad = lane >> 4;
  const int q0 = t * 128 + 32 * w;                // wave's first query
  const int ktM = min(kt1, (q0 >> 5) + 1);        // skip fully-masked tiles
  const int ktD = q0 >> 5;                        // diagonal tile index

  const bf16_t* Kt = Kf + (size_t)b * NSEQ * DIM + lane * 8;
  const bf16_t* Vt = Vf + (size_t)b * NSEQ * DIM + lane * 8;

  // Q B-frags: qf[h][d] = Q[q0+16h+l16][d*32+quad*8+j], scale folded
  bf16x8 qf[2][4];
  #pragma unroll
  for (int h = 0; h < 2; ++h) {
    const float* qrow = Qf + ((size_t)b * NSEQ + q0 + 16 * h + l16) * DIM + quad * 8;
    #pragma unroll
    for (int d = 0; d < 4; ++d) qf[h][d] = ld8_f32s(qrow + 32 * d, SCALE_LOG2E);
  }

  floatx4 acc[2][8];
  #pragma unroll
  for (int h = 0; h < 2; ++h)
    #pragma unroll
    for (int c = 0; c < 8; ++c) acc[h][c] = (floatx4){0.f, 0.f, 0.f, 0.f};
  float lsum[2] = {0.f, 0.f};
  bf16_t* pl = Pb[w];

  bf16x8 kA[8], kB[8], vC[8];

  auto loadK = [&](bf16x8* K8, int kt) {
    const bf16_t* kp = Kt + (size_t)kt * 4096;
    #pragma unroll
    for (int f = 0; f < 8; ++f) K8[f] = *(const bf16x8*)(kp + f * 512);
  };
  auto loadV = [&](int kt) {
    const bf16_t* vp = Vt + (size_t)kt * 4096;
    #pragma unroll
    for (int f = 0; f < 8; ++f) vC[f] = *(const bf16x8*)(vp + f * 512);
  };

  auto step = [&](const bf16x8* K8, int kt) {
    const bool diag = (kt == ktD);
    // ---- S^T = K Q^T : 4 independent chains of 4 ----
    floatx4 s[2][2];
    #pragma unroll
    for (int h = 0; h < 2; ++h)
      #pragma unroll
      for (int c2 = 0; c2 < 2; ++c2) s[h][c2] = (floatx4){0.f, 0.f, 0.f, 0.f};
    #pragma unroll
    for (int c2 = 0; c2 < 2; ++c2)
      #pragma unroll
      for (int d = 0; d < 4; ++d) {
        const bf16x8 kf = K8[c2 * 4 + d];
        s[0][c2] = __builtin_amdgcn_mfma_f32_16x16x32_bf16(kf, qf[0][d], s[0][c2], 0, 0, 0);
        s[1][c2] = __builtin_amdgcn_mfma_f32_16x16x32_bf16(kf, qf[1][d], s[1][c2], 0, 0, 0);
      }
    // ---- p = exp2(s); packed b64 stores: row q (stride 40 bf16), key contiguous ----
    #pragma unroll
    for (int h = 0; h < 2; ++h)
      #pragma unroll
      for (int c2 = 0; c2 < 2; ++c2) {
        float p[4];
        #pragma unroll
        for (int r = 0; r < 4; ++r) {
          float v = s[h][c2][r];
          if (diag)
            v = (c2 * 16 + quad * 4 + r <= 16 * h + l16) ? v : -3.0e38f;
          p[r] = __builtin_amdgcn_exp2f(v);
        }
        lsum[h] += (p[0] + p[1]) + (p[2] + p[3]);
        bf16x4 pk = {(__bf16)p[0], (__bf16)p[1], (__bf16)p[2], (__bf16)p[3]};
        *(bf16x4*)(pl + (16 * h + l16) * 40 + c2 * 16 + quad * 4) = pk;
      }
    asm volatile("s_waitcnt lgkmcnt(0)" ::: "memory");  // wave-private round trip
    bf16x8 pB0 = *(const bf16x8*)(pl + (l16)      * 40 + quad * 8);
    bf16x8 pB1 = *(const bf16x8*)(pl + (16 + l16) * 40 + quad * 8);
    // ---- O^T += V^T P : 16 independent MFMAs ----
    #pragma unroll
    for (int c = 0; c < 8; ++c) {
      acc[0][c] = __builtin_amdgcn_mfma_f32_16x16x32_bf16(vC[c], pB0, acc[0][c], 0, 0, 0);
      acc[1][c] = __builtin_amdgcn_mfma_f32_16x16x32_bf16(vC[c], pB1, acc[1][c], 0, 0, 0);
    }
  };

  if (kt0 < ktM) loadK(kA, kt0);
  int kt = kt0;
  while (kt < ktM) {
    loadV(kt);
    if (kt + 1 < ktM) loadK(kB, kt + 1);
    step(kA, kt);
    ++kt;
    if (kt >= ktM) break;
    loadV(kt);
    if (kt + 1 < ktM) loadK(kA, kt + 1);
    step(kB, kt);
    ++kt;
  }

  // ---- epilogue ----
  float inv_l[2];
  #pragma unroll
  for (int h = 0; h < 2; ++h) {
    float s = lsum[h];
    s += __shfl_xor(s, 16, 64);
    s += __shfl_xor(s, 32, 64);
    inv_l[h] = 1.0f / s;                          // total for q = q0+16h+l16
  }
  if (direct) {
    #pragma unroll
    for (int h = 0; h < 2; ++h) {
      float* orow = Out + ((size_t)b * NSEQ + q0 + 16 * h + l16) * DIM + quad * 4;
      #pragma unroll
      for (int c = 0; c < 8; ++c) {
        float4 o = {acc[h][c][0] * inv_l[h], acc[h][c][1] * inv_l[h],
                    acc[h][c][2] * inv_l[h], acc[h][c][3] * inv_l[h]};
        *(float4*)(orow + c * 16) = o;
      }
    }
  } else {
    // bf16 partials, row-major [q][cv]; Lpart totals (quad 0 writes)
    bf16_t* ob = Opart + pidx * 16384;
    float* lb = Lpart + pidx * 128;
    #pragma unroll
    for (int h = 0; h < 2; ++h) {
      const int row = 32 * w + 16 * h + l16;
      #pragma unroll
      for (int c = 0; c < 8; ++c) {
        bf16x4 v = {(__bf16)acc[h][c][0], (__bf16)acc[h][c][1],
                    (__bf16)acc[h][c][2], (__bf16)acc[h][c][3]};
        *(bf16x4*)(ob + (size_t)row * 128 + c * 16 + quad * 4) = v;
      }
      // store raw sum (not inverse) for cross-part addition
      if (quad == 0) lb[row] = 1.0f / inv_l[h];
    }
  }
}

// ---------------- combine: sum m parts of bf16 row-major partials ----------------
__global__ __launch_bounds__(256)
void reduce_full(const bf16_t* __restrict__ Opart, const float* __restrict__ Lpart,
                 float* __restrict__ Out) {
  __shared__ float invL[128];
  const int rb = blockIdx.x;                 // 224: b*28 + (t-4)
  const int b = rb / 28, t = 4 + rb % 28;
  const int g = t >> 2, m = g + 1;
  const size_t base = (size_t)b * 144 + 2 * g * (g + 1) + (size_t)(t - 4 * g) * m;
  const bf16_t* P = Opart + base * 16384;
  const float* L = Lpart + base * 128;
  for (int i = (int)threadIdx.x; i < 128; i += 256) {
    float l = 0.f;
    for (int p = 0; p < m; ++p) l += L[(size_t)p * 128 + i];
    invL[i] = 1.0f / l;
  }
  __syncthreads();
  float* Ob = Out + ((size_t)b * NSEQ + (size_t)t * 128) * DIM;
  for (int gi = (int)threadIdx.x; gi < 4096; gi += 256) {
    const int row = gi >> 5;
    float4 s = {0.f, 0.f, 0.f, 0.f};
    for (int p = 0; p < m; ++p) {
      bf16x4 a = *(const bf16x4*)(P + (size_t)p * 16384 + (size_t)gi * 4);
      s.x += (float)a[0]; s.y += (float)a[1]; s.z += (float)a[2]; s.w += (float)a[3];
    }
    const float inv = invL[row];
    *(float4*)(Ob + (size_t)gi * 4) =
        (float4){s.x * inv, s.y * inv, s.z * inv, s.w * inv};
  }
}

// ---------------- fallback (no workspace): fp32 direct ----------------
__global__ __launch_bounds__(256)
void causal_attn_fb(const float* __restrict__ Qf, const float* __restrict__ Kf,
                    const float* __restrict__ Vf, float* __restrict__ Out) {
  __shared__ bf16_t p_lds[4][16 * 72];
  const int bid = blockIdx.x, t = bid >> 3, b = bid & 7;
  const int tid = (int)threadIdx.x, wave = tid >> 6, lane = tid & 63;
  const int l16 = lane & 15, quad = lane >> 4;
  const int qtile = (wave < 2) ? t : (127 - t);
  const int q_base = qtile * 32 + (wave & 1) * 16;

  bf16x8 qf[4];
  const float* qrow = Qf + ((size_t)b * NSEQ + q_base + l16) * DIM + quad * 8;
  #pragma unroll
  for (int d = 0; d < 4; ++d) qf[d] = ld8_f32s(qrow + 32 * d, SCALE_LOG2E);

  floatx4 acc[8];
  #pragma unroll
  for (int c = 0; c < 8; ++c) acc[c] = (floatx4){0.f, 0.f, 0.f, 0.f};
  float lsum[4] = {0.f, 0.f, 0.f, 0.f};
  bf16_t* pl = p_lds[wave];
  const int ntiles = (q_base + 16 + 63) >> 6;

  for (int kt = 0; kt < ntiles; ++kt) {
    const int kb = kt * 64;
    floatx4 s[4];
    #pragma unroll
    for (int c4 = 0; c4 < 4; ++c4) s[c4] = (floatx4){0.f, 0.f, 0.f, 0.f};
    const float* kbase = Kf + ((size_t)b * NSEQ + kb + l16) * DIM + quad * 8;
    #pragma unroll
    for (int c4 = 0; c4 < 4; ++c4)
      #pragma unroll
      for (int d = 0; d < 4; ++d) {
        bf16x8 kf = ld8_f32s(kbase + (size_t)c4 * 16 * DIM + 32 * d, 1.0f);
        s[c4] = __builtin_amdgcn_mfma_f32_16x16x32_bf16(qf[d], kf, s[c4], 0, 0, 0);
      }
    #pragma unroll
    for (int c4 = 0; c4 < 4; ++c4)
      #pragma unroll
      for (int r = 0; r < 4; ++r) {
        float v = s[c4][r];
        const int qi = q_base + quad * 4 + r;
        v = (kb + c4 * 16 + l16 <= qi) ? v : -3.0e38f;
        float p = __builtin_amdgcn_exp2f(v);
        lsum[r] += p;
        pl[(quad * 4 + r) * 72 + c4 * 16 + l16] = (__bf16)p;
      }
    asm volatile("s_waitcnt lgkmcnt(0)" ::: "memory");
    bf16x8 pfA = *(const bf16x8*)(pl + l16 * 72 + quad * 8);
    bf16x8 pfB = *(const bf16x8*)(pl + l16 * 72 + 32 + quad * 8);
    const float* vb = Vf + ((size_t)b * NSEQ + kb) * DIM;
    #pragma unroll
    for (int c = 0; c < 8; ++c) {
      bf16x8 vfA, vfB;
      #pragma unroll
      for (int j = 0; j < 8; ++j) {
        vfA[j] = (__bf16)vb[(size_t)(quad * 8 + j) * DIM + c * 16 + l16];
        vfB[j] = (__bf16)vb[(size_t)(32 + quad * 8 + j) * DIM + c * 16 + l16];
      }
      acc[c] = __builtin_amdgcn_mfma_f32_16x16x32_bf16(pfA, vfA, acc[c], 0, 0, 0);
      acc[c] = __builtin_amdgcn_mfma_f32_16x16x32_bf16(pfB, vfB, acc[c], 0, 0, 0);
    }
  }
  float inv_l[4];
  #pragma unroll
  for (int r = 0; r < 4; ++r) {
    float s = lsum[r];
    #pragma unroll
    for (int off = 1; off < 16; off <<= 1) s += __shfl_xor(s, off, 64);
    inv_l[r] = 1.0f / s;
  }
  float* orow = Out + ((size_t)b * NSEQ + q_base + quad * 4) * DIM + l16;
  #pragma unroll
  for (int c = 0; c < 8; ++c)
    #pragma unroll
    for (int r = 0; r < 4; ++r)
      orow[(size_t)r * DIM + c * 16] = acc[c][r] * inv_l[r];
}

extern "C" void kernel_launch(void* const* d_in, const int* in_sizes, int n_in,
                              void* d_out, int out_size, void* d_ws, size_t ws_size,
                              hipStream_t stream) {
  const float* Q = (const float*)d_in[0];
  const float* K = (const float*)d_in[1];
  const float* V = (const float*)d_in[2];
  float* Out = (float*)d_out;
  (void)in_sizes; (void)n_in; (void)out_size;

  if (ws_size >= KV_BYTES) {
    bf16_t* Kf = (bf16_t*)d_ws;
    bf16_t* Vf = Kf + NELEM;
    prep_kernel<<<dim3(2048), dim3(256), 0, stream>>>(K, V, Kf, Vf);
    if (ws_size >= WS_FULL) {
      bf16_t* Opart = (bf16_t*)((char*)d_ws + KV_BYTES);
      float* Lpart = (float*)(Opart + FULL_PARTS * 16384);
      attn_kernel<<<dim3(1152), dim3(256), 0, stream>>>(Q, Kf, Vf, Out, Opart, Lpart, 2);
      reduce_full<<<dim3(224), dim3(256), 0, stream>>>(Opart, Lpart, Out);
    } else {
      attn_kernel<<<dim3(256), dim3(256), 0, stream>>>(Q, Kf, Vf, Out, nullptr, nullptr, 0);
    }
  } else {
    causal_attn_fb<<<dim3(512), dim3(256), 0, stream>>>(Q, K, V, Out);
  }
}